// Round 15
// baseline (552.930 us; speedup 1.0000x reference)
//
#include <hip/hip_runtime.h>
#include <math.h>

// Shapes (fixed by the problem)
constexpr int Bn = 4, Tn = 1024, Dn = 1024, Hn = 8, DH = 128;
constexpr float LN_EPSF = 1e-5f;

typedef __attribute__((ext_vector_type(8))) short bf16x8;   // 8 bf16 in 4 VGPRs
typedef __attribute__((ext_vector_type(4))) float f32x4;
typedef __attribute__((ext_vector_type(4))) unsigned uint4v;

#define MFMA16(a, b, c) __builtin_amdgcn_mfma_f32_16x16x32_bf16(a, b, c, 0, 0, 0)

// f32 -> bf16 round-to-nearest-even
__device__ __forceinline__ short f2bf(float f) {
    unsigned u = __builtin_bit_cast(unsigned, f);
    u += 0x7fffu + ((u >> 16) & 1u);
    return (short)(u >> 16);
}
__device__ __forceinline__ float bf2f(short h) {
    return __builtin_bit_cast(float, ((unsigned)(unsigned short)h) << 16);
}
__device__ __forceinline__ unsigned pack2(float a, float b) {
    return ((unsigned)(unsigned short)f2bf(a)) | (((unsigned)(unsigned short)f2bf(b)) << 16);
}

// async global->LDS, 16B per lane. lds ptr must be wave-uniform.
__device__ __forceinline__ void gload16(const void* g, void* l) {
    __builtin_amdgcn_global_load_lds((__attribute__((address_space(1))) void*)g,
                                     (__attribute__((address_space(3))) void*)l,
                                     16, 0, 0);
}

// Stage a 128x32 bf16 tile. LDS: [kb:4][r:128][8]; chunk c = kb*128 + r.
template <int NW>
__device__ __forceinline__ void stage_b(const short* g, int ld, short* lds, int lane, int wid) {
#pragma unroll
    for (int s = 0; s < 8 / NW; ++s) {
        const int ii = wid * (8 / NW) + s;
        const int c = ii * 64 + lane;
        const int kb = c >> 7, r = c & 127;
        gload16(g + (size_t)r * ld + kb * 8, lds + ii * 512);
    }
}

// Stage a 128x64 bf16 tile (16KB). LDS: [kb:8][r:128][8]; 1024 chunks.
template <int NT>
__device__ __forceinline__ void stage64(const short* g, int ld, short* lds, int lane, int wid) {
    constexpr int IT = 1024 / NT;   // chunk-blocks per wave
#pragma unroll
    for (int s = 0; s < IT; ++s) {
        const int cb = wid * IT + s;
        const int c = cb * 64 + lane;
        const int kb = c >> 7, r = c & 127;
        gload16(g + (size_t)r * ld + kb * 8, lds + cb * 512);
    }
}

// Stage a 128x32 f32 tile. LDS layout: [kb:4][half:2][r:128][4 f32]. 16 gload16.
template <int NW>
__device__ __forceinline__ void stage_f(const float* g, int ld, float* lds, int lane, int wid) {
#pragma unroll
    for (int s = 0; s < 16 / NW; ++s) {
        const int ii = wid * (16 / NW) + s;
        const int c = ii * 64 + lane;
        const int kb = c >> 8, half = (c >> 7) & 1, r = c & 127;
        gload16(g + (size_t)r * ld + kb * 8 + half * 4, lds + ii * 256);
    }
}

__device__ __forceinline__ bf16x8 fragb(const short* lds, int kbl, int r) {
    return *reinterpret_cast<const bf16x8*>(lds + kbl * 1024 + r * 8);
}

// fp32-staged fragment -> bf16x8 with RNE rounding
__device__ __forceinline__ bf16x8 fragf(const float* lds, int kbl, int r) {
    const f32x4 lo = *reinterpret_cast<const f32x4*>(lds + kbl * 1024 + r * 4);
    const f32x4 hi = *reinterpret_cast<const f32x4*>(lds + kbl * 1024 + 512 + r * 4);
    uint4v p;
    p[0] = pack2(lo[0], lo[1]);
    p[1] = pack2(lo[2], lo[3]);
    p[2] = pack2(hi[0], hi[1]);
    p[3] = pack2(hi[2], hi[3]);
    return __builtin_bit_cast(bf16x8, p);
}

// ---------------------------------------------------------------------------
// weights -> bf16 hi (all 6) + lo (Weq,Wek only: mats 3,4)
// ---------------------------------------------------------------------------
struct CvtP { const float* src[6]; short* hi; short* lo; };

__global__ __launch_bounds__(256) void cvt_w(CvtP p) {
    const int i = blockIdx.x * 256 + threadIdx.x;       // 786432 threads x 8 elems
    const int mat = i >> 17;
    const int off = (i & 131071) * 8;
    const float* s = p.src[mat] + off;
    const float4 a = *reinterpret_cast<const float4*>(s);
    const float4 b = *reinterpret_cast<const float4*>(s + 4);
    const float va[8] = {a.x, a.y, a.z, a.w, b.x, b.y, b.z, b.w};
    bf16x8 h, l;
#pragma unroll
    for (int j = 0; j < 8; ++j) {
        h[j] = f2bf(va[j]);
        l[j] = f2bf(va[j] - bf2f(h[j]));
    }
    *reinterpret_cast<bf16x8*>(p.hi + (size_t)mat * 1048576 + off) = h;
    if (mat == 3 || mat == 4)
        *reinterpret_cast<bf16x8*>(p.lo + (size_t)(mat - 3) * 1048576 + off) = l;
}

// ---------------------------------------------------------------------------
// x = where(pad,0,inputs) -> split bf16 (hi, lo)
// ---------------------------------------------------------------------------
__global__ __launch_bounds__(256) void mask_x(const float4* __restrict__ in,
                                              const int* __restrict__ lengths,
                                              short* __restrict__ xhi,
                                              short* __restrict__ xlo) {
    const int i = blockIdx.x * 256 + threadIdx.x;       // 1M float4
    const int row = i >> 8;
    const int t = row & 1023, b = row >> 10;
    float4 v = in[i];
    if (t >= lengths[b]) { v.x = 0.f; v.y = 0.f; v.z = 0.f; v.w = 0.f; }
    short4 h, l;
    h.x = f2bf(v.x); h.y = f2bf(v.y); h.z = f2bf(v.z); h.w = f2bf(v.w);
    l.x = f2bf(v.x - bf2f(h.x)); l.y = f2bf(v.y - bf2f(h.y));
    l.z = f2bf(v.z - bf2f(h.z)); l.w = f2bf(v.w - bf2f(h.w));
    *reinterpret_cast<short4*>(xhi + (size_t)i * 4) = h;
    *reinterpret_cast<short4*>(xlo + (size_t)i * 4) = l;
}

// ---------------------------------------------------------------------------
// proj3: q,k,v single-bf16. BK=64, 256 threads, 32KB LDS.
// z=0 q, 1 k -> [bh][t][dh]; 2 v -> transposed [bh][dh][t].
// ---------------------------------------------------------------------------
struct Proj3P { const short* w[3]; short* o[3]; };

__global__ __launch_bounds__(256) void proj3_mfma(const short* __restrict__ Xh, Proj3P p) {
    __shared__ alignas(16) short T0[8192];
    __shared__ alignas(16) short T1[8192];
    const int z = blockIdx.z;
    const short* __restrict__ Wh = p.w[z];
    const int m0 = blockIdx.y << 7, n0 = blockIdx.x << 7;
    const int tid = threadIdx.x, lane = tid & 63, wid = tid >> 6;
    const int wm = (wid >> 1) << 6, wn = (wid & 1) << 6;
    const int kbl = lane >> 4, rl = lane & 15, rw = (lane >> 4) << 2;
    f32x4 acc[4][4] = {};
    for (int k0 = 0; k0 < Dn; k0 += 64) {
        stage64<256>(Xh + (size_t)m0 * Dn + k0, Dn, T0, lane, wid);
        stage64<256>(Wh + (size_t)n0 * Dn + k0, Dn, T1, lane, wid);
        __syncthreads();
#pragma unroll
        for (int hh = 0; hh < 2; ++hh) {
            bf16x8 a[4], b[4];
#pragma unroll
            for (int f = 0; f < 4; ++f) {
                a[f] = fragb(T0, hh * 4 + kbl, wm + f * 16 + rl);
                b[f] = fragb(T1, hh * 4 + kbl, wn + f * 16 + rl);
            }
#pragma unroll
            for (int i = 0; i < 4; ++i)
#pragma unroll
                for (int j = 0; j < 4; ++j)
                    acc[i][j] = MFMA16(a[i], b[j], acc[i][j]);
        }
        __syncthreads();
    }
    short* __restrict__ O = p.o[z];
#pragma unroll
    for (int i = 0; i < 4; ++i)
#pragma unroll
        for (int r = 0; r < 4; ++r) {
            const int m = m0 + wm + i * 16 + rw + r;
            const int b = m >> 10, t = m & 1023;
#pragma unroll
            for (int j = 0; j < 4; ++j) {
                const int n = n0 + wn + j * 16 + rl;
                const int h = n >> 7, d = n & 127;
                const short val = f2bf(acc[i][j][r]);
                if (z == 2)
                    O[(((size_t)(b * Hn + h) * DH + d) << 10) + t] = val;      // Vt
                else
                    O[((((size_t)(b * Hn + h)) << 10) + t) * DH + d] = val;
            }
        }
}

// ---------------------------------------------------------------------------
// proj2: eq,ek 3-term split. BK=64, 512 threads (8 waves 2x4), 64KB LDS.
// outputs hi+lo [bh][t][dh].
// ---------------------------------------------------------------------------
struct Proj2P { const short* wh[2]; const short* wl[2]; short* oh[2]; short* ol[2]; };

__global__ __launch_bounds__(512) void proj2_mfma(const short* __restrict__ Xh,
                                                  const short* __restrict__ Xl, Proj2P p) {
    __shared__ alignas(16) short T0[8192];
    __shared__ alignas(16) short T1[8192];
    __shared__ alignas(16) short T2[8192];
    __shared__ alignas(16) short T3[8192];
    const int z = blockIdx.z;
    const short* __restrict__ Wh = p.wh[z];
    const short* __restrict__ Wl = p.wl[z];
    const int m0 = blockIdx.y << 7, n0 = blockIdx.x << 7;
    const int tid = threadIdx.x, lane = tid & 63, wid = tid >> 6;
    const int wm = (wid >> 2) << 6, wn = (wid & 3) << 5;
    const int kbl = lane >> 4, rl = lane & 15, rw = (lane >> 4) << 2;
    f32x4 acc[4][2] = {};
    for (int k0 = 0; k0 < Dn; k0 += 64) {
        stage64<512>(Xh + (size_t)m0 * Dn + k0, Dn, T0, lane, wid);
        stage64<512>(Xl + (size_t)m0 * Dn + k0, Dn, T1, lane, wid);
        stage64<512>(Wh + (size_t)n0 * Dn + k0, Dn, T2, lane, wid);
        stage64<512>(Wl + (size_t)n0 * Dn + k0, Dn, T3, lane, wid);
        __syncthreads();
#pragma unroll
        for (int hh = 0; hh < 2; ++hh) {
            bf16x8 ah[4], al[4], bh[2], bl[2];
#pragma unroll
            for (int f = 0; f < 4; ++f) {
                ah[f] = fragb(T0, hh * 4 + kbl, wm + f * 16 + rl);
                al[f] = fragb(T1, hh * 4 + kbl, wm + f * 16 + rl);
            }
#pragma unroll
            for (int f = 0; f < 2; ++f) {
                bh[f] = fragb(T2, hh * 4 + kbl, wn + f * 16 + rl);
                bl[f] = fragb(T3, hh * 4 + kbl, wn + f * 16 + rl);
            }
#pragma unroll
            for (int i = 0; i < 4; ++i)
#pragma unroll
                for (int j = 0; j < 2; ++j) {
                    acc[i][j] = MFMA16(al[i], bh[j], acc[i][j]);
                    acc[i][j] = MFMA16(ah[i], bl[j], acc[i][j]);
                    acc[i][j] = MFMA16(ah[i], bh[j], acc[i][j]);
                }
        }
        __syncthreads();
    }
    short* __restrict__ OH = p.oh[z];
    short* __restrict__ OL = p.ol[z];
#pragma unroll
    for (int i = 0; i < 4; ++i)
#pragma unroll
        for (int r = 0; r < 4; ++r) {
            const int m = m0 + wm + i * 16 + rw + r;
            const int b = m >> 10, t = m & 1023;
#pragma unroll
            for (int j = 0; j < 2; ++j) {
                const int n = n0 + wn + j * 16 + rl;
                const int h = n >> 7, d = n & 127;
                const size_t idx = (((size_t)(b * Hn + h)) << 10 | t) * DH + d;
                const float av = acc[i][j][r];
                const short hi = f2bf(av);
                OH[idx] = hi;
                OL[idx] = f2bf(av - bf2f(hi));
            }
        }
}

// ---------------------------------------------------------------------------
// scores_edge (R14 structure, E-write epilogue): two sequential GEMM phases,
// single lean end epilogue. phase A: edge = eq ek^T (3-term split);
// phase B: scores = q k^T. epilogue: p = sigmoid(edge) -> EP; gate =
// (p + u > 1) [exact algebraic form of the reference binary-concrete gate];
// E = exp(s/32) (0 if masked) -> attn slot (no row max needed: |s| <= ~1);
// inline expsum partial per (row, col-half) -> Sl.
// ---------------------------------------------------------------------------
__global__ __launch_bounds__(256) void scores_edge(
    const short* __restrict__ Q, const short* __restrict__ Kb,
    const short* __restrict__ EQh, const short* __restrict__ EQl,
    const short* __restrict__ EKh, const short* __restrict__ EKl,
    const float* __restrict__ U, const int* __restrict__ lens,
    float* __restrict__ S, float* __restrict__ EP,
    float* __restrict__ Sl) {
    __shared__ alignas(16) short T0[4096];
    __shared__ alignas(16) short T1[4096];
    __shared__ alignas(16) short T2[4096];
    __shared__ alignas(16) short T3[4096];
    const int z = blockIdx.z;
    const int len = lens[z >> 3];
    const int m0 = blockIdx.y << 7, n0 = blockIdx.x << 7;
    const int tid = threadIdx.x, lane = tid & 63, wid = tid >> 6;
    const int wm = (wid >> 1) << 6, wn = (wid & 1) << 6;
    const int kbl = lane >> 4, rl = lane & 15, rw = (lane >> 4) << 2;
    const size_t zo = (size_t)z << 17;   // z*T*DH

    // phase A: edge, 3-term split
    f32x4 acce[4][4] = {};
    for (int k0 = 0; k0 < DH; k0 += 32) {
        stage_b<4>(EQh + zo + (size_t)m0 * DH + k0, DH, T0, lane, wid);
        stage_b<4>(EQl + zo + (size_t)m0 * DH + k0, DH, T1, lane, wid);
        stage_b<4>(EKh + zo + (size_t)n0 * DH + k0, DH, T2, lane, wid);
        stage_b<4>(EKl + zo + (size_t)n0 * DH + k0, DH, T3, lane, wid);
        __syncthreads();
        bf16x8 ah[4], al[4], bh[4], bl[4];
#pragma unroll
        for (int f = 0; f < 4; ++f) {
            ah[f] = fragb(T0, kbl, wm + f * 16 + rl);
            al[f] = fragb(T1, kbl, wm + f * 16 + rl);
            bh[f] = fragb(T2, kbl, wn + f * 16 + rl);
            bl[f] = fragb(T3, kbl, wn + f * 16 + rl);
        }
#pragma unroll
        for (int i = 0; i < 4; ++i)
#pragma unroll
            for (int j = 0; j < 4; ++j) {
                acce[i][j] = MFMA16(al[i], bh[j], acce[i][j]);
                acce[i][j] = MFMA16(ah[i], bl[j], acce[i][j]);
                acce[i][j] = MFMA16(ah[i], bh[j], acce[i][j]);
            }
        __syncthreads();
    }

    // phase B: scores, single bf16 (reuses T0/T1)
    f32x4 accs[4][4] = {};
    for (int k0 = 0; k0 < DH; k0 += 32) {
        stage_b<4>(Q + zo + (size_t)m0 * DH + k0, DH, T0, lane, wid);
        stage_b<4>(Kb + zo + (size_t)n0 * DH + k0, DH, T1, lane, wid);
        __syncthreads();
        bf16x8 a[4], b[4];
#pragma unroll
        for (int f = 0; f < 4; ++f) {
            a[f] = fragb(T0, kbl, wm + f * 16 + rl);
            b[f] = fragb(T1, kbl, wn + f * 16 + rl);
        }
#pragma unroll
        for (int i = 0; i < 4; ++i)
#pragma unroll
            for (int j = 0; j < 4; ++j)
                accs[i][j] = MFMA16(a[i], b[j], accs[i][j]);
        __syncthreads();
    }

    // epilogue: EP + algebraic gate + E-write + inline expsum partial
    const size_t part = ((size_t)(z * 16 + blockIdx.x * 2 + (wn >> 6)) << 10);
#pragma unroll
    for (int i = 0; i < 4; ++i)
#pragma unroll
        for (int r = 0; r < 4; ++r) {
            const int m = m0 + wm + i * 16 + rw + r;
            float ls = 0.f;
#pragma unroll
            for (int j = 0; j < 4; ++j) {
                const int n = n0 + wn + j * 16 + rl;
                const size_t idx = ((size_t)z << 20) + ((size_t)m << 10) + n;
                const float pp = 1.f / (1.f + __expf(-acce[i][j][r]));
                EP[idx] = pp;
                // reference gate zz>0 <=> (p+eps)(u+eps) > (1-p+eps)(1-u+eps)
                //                     <=> (p+u-1)(1+2eps) > 0 <=> p+u > 1
                const bool valid = (pp + U[idx] > 1.f) && (n < len);
                const float E = valid ? __expf(accs[i][j][r] * (1.f / 32.f)) : 0.f;
                S[idx] = E;
                ls += E;
            }
            // expsum partial over this 64-key half (16 lanes share the row)
#pragma unroll
            for (int off = 1; off <= 8; off <<= 1) ls += __shfl_xor(ls, off);
            if (rl == 0) Sl[part + m] = ls;
        }
}

// ---------------------------------------------------------------------------
// Fused softmax-normalize + ctx. Phase 1: L = sum of 16 expsum partials per
// row; P = E * (1/L) in place (pure multiply). Phase 2: ctx = relu(P @ V).
// ---------------------------------------------------------------------------
__global__ __launch_bounds__(512) void softmax_ctx(float* __restrict__ P,
                                                   const float* __restrict__ Sl,
                                                   const short* __restrict__ Vt,
                                                   float* __restrict__ C) {
    __shared__ alignas(16) float Ps[4096];
    __shared__ alignas(16) short Vs[4096];
    const int z = blockIdx.y;
    const int bb = z >> 3, h = z & 7;
    const int m0 = blockIdx.x << 7;
    const int tid = threadIdx.x, lane = tid & 63, wid = tid >> 6;

    {
        const int r = tid >> 2, qd = tid & 3;
        const int row = m0 + r;
        float L = 0.f;
#pragma unroll
        for (int t = 0; t < 16; ++t) L += Sl[((size_t)(z * 16 + t) << 10) + row];
        const float inv = (L > 0.f) ? 1.f / L : 0.f;
        float* rowp = P + ((size_t)z << 20) + ((size_t)row << 10) + qd * 8;
#pragma unroll 8
        for (int c = 0; c < 32; ++c) {
            float4 v0 = *reinterpret_cast<const float4*>(rowp + c * 32);
            float4 v1 = *reinterpret_cast<const float4*>(rowp + c * 32 + 4);
            v0.x *= inv; v0.y *= inv; v0.z *= inv; v0.w *= inv;
            v1.x *= inv; v1.y *= inv; v1.z *= inv; v1.w *= inv;
            *reinterpret_cast<float4*>(rowp + c * 32) = v0;
            *reinterpret_cast<float4*>(rowp + c * 32 + 4) = v1;
        }
    }
    __syncthreads();

    // phase 2: ctx GEMM
    const int wm = (wid >> 2) << 6, wn = (wid & 3) << 5;
    const int kbl = lane >> 4, rl = lane & 15, rw = (lane >> 4) << 2;
    f32x4 acc[4][2] = {};
    for (int k0 = 0; k0 < Tn; k0 += 32) {
        stage_f<8>(P + ((size_t)z << 20) + ((size_t)m0 << 10) + k0, Tn, Ps, lane, wid);
        stage_b<8>(Vt + ((size_t)z << 17) + k0, Tn, Vs, lane, wid);
        __syncthreads();
        bf16x8 a[4], b[2];
#pragma unroll
        for (int f = 0; f < 4; ++f) a[f] = fragf(Ps, kbl, wm + f * 16 + rl);
#pragma unroll
        for (int f = 0; f < 2; ++f) b[f] = fragb(Vs, kbl, wn + f * 16 + rl);
#pragma unroll
        for (int i = 0; i < 4; ++i)
#pragma unroll
            for (int j = 0; j < 2; ++j)
                acc[i][j] = MFMA16(a[i], b[j], acc[i][j]);
        __syncthreads();
    }
#pragma unroll
    for (int i = 0; i < 4; ++i)
#pragma unroll
        for (int r = 0; r < 4; ++r) {
            const int m = m0 + wm + i * 16 + rw + r;
#pragma unroll
            for (int j = 0; j < 2; ++j) {
                const int n = wn + j * 16 + rl;
                C[(((size_t)(bb << 10 | m)) << 10) + h * DH + n] = fmaxf(acc[i][j][r], 0.f);
            }
        }
}

// ---------------------------------------------------------------------------
// h1 = LN(ctx + masked_inputs); emits fp32 + bf16 (hi only)
// ---------------------------------------------------------------------------
__global__ __launch_bounds__(256) void ln1_kernel(const float* __restrict__ ctx,
                                                  const float* __restrict__ inputs,
                                                  const int* __restrict__ lengths,
                                                  const float* __restrict__ g,
                                                  const float* __restrict__ bb,
                                                  float* __restrict__ h1f,
                                                  short* __restrict__ h1hi) {
    __shared__ float red1[4];
    __shared__ float red2[4];
    const int row = blockIdx.x;
    const int t = row & 1023, b = row >> 10;
    const bool live = t < lengths[b];
    const size_t base = (size_t)row * Dn;
    const int tid = threadIdx.x;
    float4 v = reinterpret_cast<const float4*>(ctx + base)[tid];
    if (live) {
        const float4 r = reinterpret_cast<const float4*>(inputs + base)[tid];
        v.x += r.x; v.y += r.y; v.z += r.z; v.w += r.w;
    }
    float s = v.x + v.y + v.z + v.w;
#pragma unroll
    for (int off = 32; off >= 1; off >>= 1) s += __shfl_xor(s, off);
    if ((tid & 63) == 0) red1[tid >> 6] = s;
    __syncthreads();
    const float mu = (red1[0] + red1[1] + red1[2] + red1[3]) * (1.f / Dn);
    const float d0 = v.x - mu, d1 = v.y - mu, d2 = v.z - mu, d3 = v.w - mu;
    float sq = d0 * d0 + d1 * d1 + d2 * d2 + d3 * d3;
#pragma unroll
    for (int off = 32; off >= 1; off >>= 1) sq += __shfl_xor(sq, off);
    if ((tid & 63) == 0) red2[tid >> 6] = sq;
    __syncthreads();
    const float var = (red2[0] + red2[1] + red2[2] + red2[3]) * (1.f / Dn);
    const float rstd = rsqrtf(var + LN_EPSF);
    const float4 gv = reinterpret_cast<const float4*>(g)[tid];
    const float4 bv = reinterpret_cast<const float4*>(bb)[tid];
    float4 ov;
    ov.x = d0 * rstd * gv.x + bv.x;
    ov.y = d1 * rstd * gv.y + bv.y;
    ov.z = d2 * rstd * gv.z + bv.z;
    ov.w = d3 * rstd * gv.w + bv.w;
    reinterpret_cast<float4*>(h1f + base)[tid] = ov;
    short4 hs;
    hs.x = f2bf(ov.x); hs.y = f2bf(ov.y); hs.z = f2bf(ov.z); hs.w = f2bf(ov.w);
    reinterpret_cast<short4*>(h1hi + base)[tid] = hs;
}

// ---------------------------------------------------------------------------
// h2 = relu(h1 @ Wfc^T + bfc) + h1 ; single bf16; BK=64; 256 threads; 32KB LDS
// ---------------------------------------------------------------------------
__global__ __launch_bounds__(256) void fc_mfma(const short* __restrict__ Xh,
                                               const short* __restrict__ Wh,
                                               const float* __restrict__ bias,
                                               const float* __restrict__ H1f,
                                               float* __restrict__ O) {
    __shared__ alignas(16) short T0[8192];
    __shared__ alignas(16) short T1[8192];
    const int m0 = blockIdx.y << 7, n0 = blockIdx.x << 7;
    const int tid = threadIdx.x, lane = tid & 63, wid = tid >> 6;
    const int wm = (wid >> 1) << 6, wn = (wid & 1) << 6;
    const int kbl = lane >> 4, rl = lane & 15, rw = (lane >> 4) << 2;
    f32x4 acc[4][4] = {};
    for (int k0 = 0; k0 < Dn; k0 += 64) {
        stage64<256>(Xh + (size_t)m0 * Dn + k0, Dn, T0, lane, wid);
        stage64<256>(Wh + (size_t)n0 * Dn + k0, Dn, T1, lane, wid);
        __syncthreads();
#pragma unroll
        for (int hh = 0; hh < 2; ++hh) {
            bf16x8 a[4], b[4];
#pragma unroll
            for (int f = 0; f < 4; ++f) {
                a[f] = fragb(T0, hh * 4 + kbl, wm + f * 16 + rl);
                b[f] = fragb(T1, hh * 4 + kbl, wn + f * 16 + rl);
            }
#pragma unroll
            for (int i = 0; i < 4; ++i)
#pragma unroll
                for (int j = 0; j < 4; ++j)
                    acc[i][j] = MFMA16(a[i], b[j], acc[i][j]);
        }
        __syncthreads();
    }
#pragma unroll
    for (int i = 0; i < 4; ++i)
#pragma unroll
        for (int r = 0; r < 4; ++r) {
            const int m = m0 + wm + i * 16 + rw + r;
#pragma unroll
            for (int j = 0; j < 4; ++j) {
                const int n = n0 + wn + j * 16 + rl;
                const size_t idx = ((size_t)m << 10) + n;
                O[idx] = fmaxf(acc[i][j][r] + bias[n], 0.f) + H1f[idx];
            }
        }
}

// ---------------------------------------------------------------------------
// out = LN(h2), zero padded rows
// ---------------------------------------------------------------------------
__global__ __launch_bounds__(256) void ln2_kernel(const float* __restrict__ a,
                                                  const float* __restrict__ g,
                                                  const float* __restrict__ bb,
                                                  const int* __restrict__ lengths,
                                                  float* __restrict__ o) {
    __shared__ float red1[4];
    __shared__ float red2[4];
    const int row = blockIdx.x;
    const size_t base = (size_t)row * Dn;
    const int tid = threadIdx.x;
    float4 v = reinterpret_cast<const float4*>(a + base)[tid];
    float s = v.x + v.y + v.z + v.w;
#pragma unroll
    for (int off = 32; off >= 1; off >>= 1) s += __shfl_xor(s, off);
    if ((tid & 63) == 0) red1[tid >> 6] = s;
    __syncthreads();
    const float mu = (red1[0] + red1[1] + red1[2] + red1[3]) * (1.f / Dn);
    const float d0 = v.x - mu, d1 = v.y - mu, d2 = v.z - mu, d3 = v.w - mu;
    float sq = d0 * d0 + d1 * d1 + d2 * d2 + d3 * d3;
#pragma unroll
    for (int off = 32; off >= 1; off >>= 1) sq += __shfl_xor(sq, off);
    if ((tid & 63) == 0) red2[tid >> 6] = sq;
    __syncthreads();
    const float var = (red2[0] + red2[1] + red2[2] + red2[3]) * (1.f / Dn);
    const float rstd = rsqrtf(var + LN_EPSF);
    const float4 gv = reinterpret_cast<const float4*>(g)[tid];
    const float4 bv = reinterpret_cast<const float4*>(bb)[tid];
    float4 ov;
    ov.x = d0 * rstd * gv.x + bv.x;
    ov.y = d1 * rstd * gv.y + bv.y;
    ov.z = d2 * rstd * gv.z + bv.z;
    ov.w = d3 * rstd * gv.w + bv.w;
    const int t = row & 1023, b = row >> 10;
    if (t >= lengths[b]) { ov.x = 0.f; ov.y = 0.f; ov.z = 0.f; ov.w = 0.f; }
    reinterpret_cast<float4*>(o + base)[tid] = ov;
}

// ---------------------------------------------------------------------------
extern "C" void kernel_launch(void* const* d_in, const int* in_sizes, int n_in,
                              void* d_out, int out_size, void* d_ws, size_t ws_size,
                              hipStream_t stream) {
    const float* inputs = (const float*)d_in[0];
    const int* lengths = (const int*)d_in[1];
    const float* noise = (const float*)d_in[2];
    const float* bfc = (const float*)d_in[9];
    const float* ln1_g = (const float*)d_in[10];
    const float* ln1_b = (const float*)d_in[11];
    const float* ln2_g = (const float*)d_in[12];
    const float* ln2_b = (const float*)d_in[13];

    float* out = (float*)d_out;                       // (B,T,D)   4M f32
    float* attn = out + (size_t)Bn * Tn * Dn;         // (B,H,T,T) 32M f32
    float* ep = attn + (size_t)Bn * Hn * Tn * Tn;     // (B,H,T,T) 32M f32

    // workspace layout, peak 92 MB
    constexpr size_t MB = 1u << 20;
    char* W = (char*)d_ws;
    short* xhi = (short*)(W + 0 * MB);        //  8MB (dead after proj)
    short* xlo = (short*)(W + 8 * MB);        //  8MB (dead after proj)
    short* whi = (short*)(W + 16 * MB);       // 12MB hi of all 6 weights
    short* wlo = (short*)(W + 28 * MB);       //  4MB lo of Weq,Wek
    short* qb = (short*)(W + 34 * MB);        //  8MB (dead after scores_edge)
    short* kb = (short*)(W + 42 * MB);        //  8MB (dead after scores_edge)
    short* vtb = (short*)(W + 50 * MB);       //  8MB (dead after softmax_ctx)
    short* eqh = (short*)(W + 58 * MB);       //  8MB, dead after scores_edge
    short* eql = (short*)(W + 66 * MB);       //  8MB, dead after scores_edge
    short* ekh = (short*)(W + 74 * MB);       //  8MB, dead after scores_edge
    short* ekl = (short*)(W + 82 * MB);       //  8MB, dead after scores_edge
    float* ctx = (float*)(W + 58 * MB);       // 16MB reuse eqh+eql
    float* h1f = (float*)(W + 74 * MB);       // 16MB reuse ekh+ekl
    short* h1hi = (short*)(W + 34 * MB);      //  8MB reuse qb
    float* h2 = (float*)(W + 0 * MB);         // 16MB reuse xhi+xlo
    float* Sl = (float*)(W + 90 * MB);        //  2MB softmax half-tile expsums

    // K0: weights -> bf16 hi/lo
    CvtP cp;
    for (int j = 0; j < 6; ++j) cp.src[j] = (const float*)d_in[3 + j];
    cp.hi = whi; cp.lo = wlo;
    cvt_w<<<dim3(3072), 256, 0, stream>>>(cp);

    // K1: masked x -> split bf16
    mask_x<<<dim3(4096), 256, 0, stream>>>((const float4*)inputs, lengths, xhi, xlo);

    // K2a: q,k,v projections (single bf16, BK=64)
    Proj3P p3;
    p3.w[0] = whi;                 p3.o[0] = qb;
    p3.w[1] = whi + 1 * 1048576;   p3.o[1] = kb;
    p3.w[2] = whi + 2 * 1048576;   p3.o[2] = vtb;
    proj3_mfma<<<dim3(8, 32, 3), 256, 0, stream>>>(xhi, p3);

    // K2b: eq,ek projections (3-term split, BK=64, 512 threads)
    Proj2P p2;
    p2.wh[0] = whi + 3 * 1048576;  p2.wl[0] = wlo;
    p2.wh[1] = whi + 4 * 1048576;  p2.wl[1] = wlo + 1048576;
    p2.oh[0] = eqh; p2.ol[0] = eql;
    p2.oh[1] = ekh; p2.ol[1] = ekl;
    proj2_mfma<<<dim3(8, 32, 2), 512, 0, stream>>>(xhi, xlo, p2);

    // K3: edge(3-term)+scores, lean E-write epilogue + expsum partials
    scores_edge<<<dim3(8, 8, 32), 256, 0, stream>>>(qb, kb, eqh, eql, ekh, ekl,
                                                    noise, lengths, attn, ep, Sl);

    // K4: normalize (multiply by 1/L) + ctx GEMM
    softmax_ctx<<<dim3(8, 32), 512, 0, stream>>>(attn, Sl, vtb, ctx);

    // K5: h1 = LN(ctx + masked inputs) -> fp32 + bf16
    ln1_kernel<<<dim3(Bn * Tn), 256, 0, stream>>>(ctx, inputs, lengths, ln1_g, ln1_b,
                                                  h1f, h1hi);

    // K6: h2 = relu(h1 @ Wfc^T + bfc) + h1 (single bf16, BK=64)
    fc_mfma<<<dim3(8, 32), 256, 0, stream>>>(h1hi, whi + 5 * 1048576, bfc, h1f, h2);

    // K7: out = LN(h2), zero padded rows
    ln2_kernel<<<dim3(Bn * Tn), 256, 0, stream>>>(h2, ln2_g, ln2_b, lengths, out);
}

// Round 16
// 489.670 us; speedup vs baseline: 1.1292x; 1.1292x over previous
//
#include <hip/hip_runtime.h>
#include <math.h>

// Shapes (fixed by the problem)
constexpr int Bn = 4, Tn = 1024, Dn = 1024, Hn = 8, DH = 128;
constexpr float LN_EPSF = 1e-5f;
constexpr float NEGF = -1e30f;

typedef __attribute__((ext_vector_type(8))) short bf16x8;   // 8 bf16 in 4 VGPRs
typedef __attribute__((ext_vector_type(4))) float f32x4;
typedef __attribute__((ext_vector_type(4))) unsigned uint4v;

#define MFMA16(a, b, c) __builtin_amdgcn_mfma_f32_16x16x32_bf16(a, b, c, 0, 0, 0)

// f32 -> bf16 round-to-nearest-even
__device__ __forceinline__ short f2bf(float f) {
    unsigned u = __builtin_bit_cast(unsigned, f);
    u += 0x7fffu + ((u >> 16) & 1u);
    return (short)(u >> 16);
}
__device__ __forceinline__ float bf2f(short h) {
    return __builtin_bit_cast(float, ((unsigned)(unsigned short)h) << 16);
}
__device__ __forceinline__ unsigned pack2(float a, float b) {
    return ((unsigned)(unsigned short)f2bf(a)) | (((unsigned)(unsigned short)f2bf(b)) << 16);
}

// async global->LDS, 16B per lane. lds ptr must be wave-uniform.
__device__ __forceinline__ void gload16(const void* g, void* l) {
    __builtin_amdgcn_global_load_lds((__attribute__((address_space(1))) void*)g,
                                     (__attribute__((address_space(3))) void*)l,
                                     16, 0, 0);
}

// Stage a 128x32 bf16 tile. LDS: [kb:4][r:128][8]; chunk c = kb*128 + r.
template <int NW>
__device__ __forceinline__ void stage_b(const short* g, int ld, short* lds, int lane, int wid) {
#pragma unroll
    for (int s = 0; s < 8 / NW; ++s) {
        const int ii = wid * (8 / NW) + s;
        const int c = ii * 64 + lane;
        const int kb = c >> 7, r = c & 127;
        gload16(g + (size_t)r * ld + kb * 8, lds + ii * 512);
    }
}

// Stage a 128x64 bf16 tile (16KB). LDS: [kb:8][r:128][8]; 1024 chunks.
template <int NT>
__device__ __forceinline__ void stage64(const short* g, int ld, short* lds, int lane, int wid) {
    constexpr int IT = 1024 / NT;   // chunk-blocks per wave
#pragma unroll
    for (int s = 0; s < IT; ++s) {
        const int cb = wid * IT + s;
        const int c = cb * 64 + lane;
        const int kb = c >> 7, r = c & 127;
        gload16(g + (size_t)r * ld + kb * 8, lds + cb * 512);
    }
}

// Stage a 128x32 f32 tile. LDS layout: [kb:4][half:2][r:128][4 f32]. 16 gload16.
template <int NW>
__device__ __forceinline__ void stage_f(const float* g, int ld, float* lds, int lane, int wid) {
#pragma unroll
    for (int s = 0; s < 16 / NW; ++s) {
        const int ii = wid * (16 / NW) + s;
        const int c = ii * 64 + lane;
        const int kb = c >> 8, half = (c >> 7) & 1, r = c & 127;
        gload16(g + (size_t)r * ld + kb * 8 + half * 4, lds + ii * 256);
    }
}

__device__ __forceinline__ bf16x8 fragb(const short* lds, int kbl, int r) {
    return *reinterpret_cast<const bf16x8*>(lds + kbl * 1024 + r * 8);
}

// fp32-staged fragment -> bf16x8 with RNE rounding
__device__ __forceinline__ bf16x8 fragf(const float* lds, int kbl, int r) {
    const f32x4 lo = *reinterpret_cast<const f32x4*>(lds + kbl * 1024 + r * 4);
    const f32x4 hi = *reinterpret_cast<const f32x4*>(lds + kbl * 1024 + 512 + r * 4);
    uint4v p;
    p[0] = pack2(lo[0], lo[1]);
    p[1] = pack2(lo[2], lo[3]);
    p[2] = pack2(hi[0], hi[1]);
    p[3] = pack2(hi[2], hi[3]);
    return __builtin_bit_cast(bf16x8, p);
}

// ---------------------------------------------------------------------------
// weights -> bf16 hi (all 6) + lo (Weq,Wek only: mats 3,4)
// ---------------------------------------------------------------------------
struct CvtP { const float* src[6]; short* hi; short* lo; };

__global__ __launch_bounds__(256) void cvt_w(CvtP p) {
    const int i = blockIdx.x * 256 + threadIdx.x;       // 786432 threads x 8 elems
    const int mat = i >> 17;
    const int off = (i & 131071) * 8;
    const float* s = p.src[mat] + off;
    const float4 a = *reinterpret_cast<const float4*>(s);
    const float4 b = *reinterpret_cast<const float4*>(s + 4);
    const float va[8] = {a.x, a.y, a.z, a.w, b.x, b.y, b.z, b.w};
    bf16x8 h, l;
#pragma unroll
    for (int j = 0; j < 8; ++j) {
        h[j] = f2bf(va[j]);
        l[j] = f2bf(va[j] - bf2f(h[j]));
    }
    *reinterpret_cast<bf16x8*>(p.hi + (size_t)mat * 1048576 + off) = h;
    if (mat == 3 || mat == 4)
        *reinterpret_cast<bf16x8*>(p.lo + (size_t)(mat - 3) * 1048576 + off) = l;
}

// ---------------------------------------------------------------------------
// x = where(pad,0,inputs) -> split bf16 (hi, lo)
// ---------------------------------------------------------------------------
__global__ __launch_bounds__(256) void mask_x(const float4* __restrict__ in,
                                              const int* __restrict__ lengths,
                                              short* __restrict__ xhi,
                                              short* __restrict__ xlo) {
    const int i = blockIdx.x * 256 + threadIdx.x;       // 1M float4
    const int row = i >> 8;
    const int t = row & 1023, b = row >> 10;
    float4 v = in[i];
    if (t >= lengths[b]) { v.x = 0.f; v.y = 0.f; v.z = 0.f; v.w = 0.f; }
    short4 h, l;
    h.x = f2bf(v.x); h.y = f2bf(v.y); h.z = f2bf(v.z); h.w = f2bf(v.w);
    l.x = f2bf(v.x - bf2f(h.x)); l.y = f2bf(v.y - bf2f(h.y));
    l.z = f2bf(v.z - bf2f(h.z)); l.w = f2bf(v.w - bf2f(h.w));
    *reinterpret_cast<short4*>(xhi + (size_t)i * 4) = h;
    *reinterpret_cast<short4*>(xlo + (size_t)i * 4) = l;
}

// ---------------------------------------------------------------------------
// proj3: q,k,v single-bf16. BK=64, 256 threads, 32KB LDS.
// z=0 q, 1 k -> [bh][t][dh]; 2 v -> transposed [bh][dh][t].
// ---------------------------------------------------------------------------
struct Proj3P { const short* w[3]; short* o[3]; };

__global__ __launch_bounds__(256) void proj3_mfma(const short* __restrict__ Xh, Proj3P p) {
    __shared__ alignas(16) short T0[8192];
    __shared__ alignas(16) short T1[8192];
    const int z = blockIdx.z;
    const short* __restrict__ Wh = p.w[z];
    const int m0 = blockIdx.y << 7, n0 = blockIdx.x << 7;
    const int tid = threadIdx.x, lane = tid & 63, wid = tid >> 6;
    const int wm = (wid >> 1) << 6, wn = (wid & 1) << 6;
    const int kbl = lane >> 4, rl = lane & 15, rw = (lane >> 4) << 2;
    f32x4 acc[4][4] = {};
    for (int k0 = 0; k0 < Dn; k0 += 64) {
        stage64<256>(Xh + (size_t)m0 * Dn + k0, Dn, T0, lane, wid);
        stage64<256>(Wh + (size_t)n0 * Dn + k0, Dn, T1, lane, wid);
        __syncthreads();
#pragma unroll
        for (int hh = 0; hh < 2; ++hh) {
            bf16x8 a[4], b[4];
#pragma unroll
            for (int f = 0; f < 4; ++f) {
                a[f] = fragb(T0, hh * 4 + kbl, wm + f * 16 + rl);
                b[f] = fragb(T1, hh * 4 + kbl, wn + f * 16 + rl);
            }
#pragma unroll
            for (int i = 0; i < 4; ++i)
#pragma unroll
                for (int j = 0; j < 4; ++j)
                    acc[i][j] = MFMA16(a[i], b[j], acc[i][j]);
        }
        __syncthreads();
    }
    short* __restrict__ O = p.o[z];
#pragma unroll
    for (int i = 0; i < 4; ++i)
#pragma unroll
        for (int r = 0; r < 4; ++r) {
            const int m = m0 + wm + i * 16 + rw + r;
            const int b = m >> 10, t = m & 1023;
#pragma unroll
            for (int j = 0; j < 4; ++j) {
                const int n = n0 + wn + j * 16 + rl;
                const int h = n >> 7, d = n & 127;
                const short val = f2bf(acc[i][j][r]);
                if (z == 2)
                    O[(((size_t)(b * Hn + h) * DH + d) << 10) + t] = val;      // Vt
                else
                    O[((((size_t)(b * Hn + h)) << 10) + t) * DH + d] = val;
            }
        }
}

// ---------------------------------------------------------------------------
// proj2: eq,ek 3-term split. BK=64, 512 threads (8 waves 2x4), 64KB LDS.
// outputs hi+lo [bh][t][dh].
// ---------------------------------------------------------------------------
struct Proj2P { const short* wh[2]; const short* wl[2]; short* oh[2]; short* ol[2]; };

__global__ __launch_bounds__(512) void proj2_mfma(const short* __restrict__ Xh,
                                                  const short* __restrict__ Xl, Proj2P p) {
    __shared__ alignas(16) short T0[8192];
    __shared__ alignas(16) short T1[8192];
    __shared__ alignas(16) short T2[8192];
    __shared__ alignas(16) short T3[8192];
    const int z = blockIdx.z;
    const short* __restrict__ Wh = p.wh[z];
    const short* __restrict__ Wl = p.wl[z];
    const int m0 = blockIdx.y << 7, n0 = blockIdx.x << 7;
    const int tid = threadIdx.x, lane = tid & 63, wid = tid >> 6;
    const int wm = (wid >> 2) << 6, wn = (wid & 3) << 5;
    const int kbl = lane >> 4, rl = lane & 15, rw = (lane >> 4) << 2;
    f32x4 acc[4][2] = {};
    for (int k0 = 0; k0 < Dn; k0 += 64) {
        stage64<512>(Xh + (size_t)m0 * Dn + k0, Dn, T0, lane, wid);
        stage64<512>(Xl + (size_t)m0 * Dn + k0, Dn, T1, lane, wid);
        stage64<512>(Wh + (size_t)n0 * Dn + k0, Dn, T2, lane, wid);
        stage64<512>(Wl + (size_t)n0 * Dn + k0, Dn, T3, lane, wid);
        __syncthreads();
#pragma unroll
        for (int hh = 0; hh < 2; ++hh) {
            bf16x8 ah[4], al[4], bh[2], bl[2];
#pragma unroll
            for (int f = 0; f < 4; ++f) {
                ah[f] = fragb(T0, hh * 4 + kbl, wm + f * 16 + rl);
                al[f] = fragb(T1, hh * 4 + kbl, wm + f * 16 + rl);
            }
#pragma unroll
            for (int f = 0; f < 2; ++f) {
                bh[f] = fragb(T2, hh * 4 + kbl, wn + f * 16 + rl);
                bl[f] = fragb(T3, hh * 4 + kbl, wn + f * 16 + rl);
            }
#pragma unroll
            for (int i = 0; i < 4; ++i)
#pragma unroll
                for (int j = 0; j < 2; ++j) {
                    acc[i][j] = MFMA16(al[i], bh[j], acc[i][j]);
                    acc[i][j] = MFMA16(ah[i], bl[j], acc[i][j]);
                    acc[i][j] = MFMA16(ah[i], bh[j], acc[i][j]);
                }
        }
        __syncthreads();
    }
    short* __restrict__ OH = p.oh[z];
    short* __restrict__ OL = p.ol[z];
#pragma unroll
    for (int i = 0; i < 4; ++i)
#pragma unroll
        for (int r = 0; r < 4; ++r) {
            const int m = m0 + wm + i * 16 + rw + r;
            const int b = m >> 10, t = m & 1023;
#pragma unroll
            for (int j = 0; j < 2; ++j) {
                const int n = n0 + wn + j * 16 + rl;
                const int h = n >> 7, d = n & 127;
                const size_t idx = (((size_t)(b * Hn + h)) << 10 | t) * DH + d;
                const float av = acc[i][j][r];
                const short hi = f2bf(av);
                OH[idx] = hi;
                OL[idx] = f2bf(av - bf2f(hi));
            }
        }
}

// ---------------------------------------------------------------------------
// scores_edge (R14, best measured): two sequential GEMM phases, single end
// epilogue. phase A: edge = eq ek^T (3-term split); phase B: scores = q k^T.
// epilogue: p = sigmoid(edge) -> EP; gate = (p + u > 1) [exact algebraic
// form of the reference binary-concrete gate]; masked raw scores -> attn;
// per-(row, col-half) softmax partials (max, expsum) -> Sm/Sl.
// ---------------------------------------------------------------------------
__global__ __launch_bounds__(256) void scores_edge(
    const short* __restrict__ Q, const short* __restrict__ Kb,
    const short* __restrict__ EQh, const short* __restrict__ EQl,
    const short* __restrict__ EKh, const short* __restrict__ EKl,
    const float* __restrict__ U, const int* __restrict__ lens,
    float* __restrict__ S, float* __restrict__ EP,
    float* __restrict__ Sm, float* __restrict__ Sl) {
    __shared__ alignas(16) short T0[4096];
    __shared__ alignas(16) short T1[4096];
    __shared__ alignas(16) short T2[4096];
    __shared__ alignas(16) short T3[4096];
    const int z = blockIdx.z;
    const int len = lens[z >> 3];
    const int m0 = blockIdx.y << 7, n0 = blockIdx.x << 7;
    const int tid = threadIdx.x, lane = tid & 63, wid = tid >> 6;
    const int wm = (wid >> 1) << 6, wn = (wid & 1) << 6;
    const int kbl = lane >> 4, rl = lane & 15, rw = (lane >> 4) << 2;
    const size_t zo = (size_t)z << 17;   // z*T*DH

    // phase A: edge, 3-term split
    f32x4 acce[4][4] = {};
    for (int k0 = 0; k0 < DH; k0 += 32) {
        stage_b<4>(EQh + zo + (size_t)m0 * DH + k0, DH, T0, lane, wid);
        stage_b<4>(EQl + zo + (size_t)m0 * DH + k0, DH, T1, lane, wid);
        stage_b<4>(EKh + zo + (size_t)n0 * DH + k0, DH, T2, lane, wid);
        stage_b<4>(EKl + zo + (size_t)n0 * DH + k0, DH, T3, lane, wid);
        __syncthreads();
        bf16x8 ah[4], al[4], bh[4], bl[4];
#pragma unroll
        for (int f = 0; f < 4; ++f) {
            ah[f] = fragb(T0, kbl, wm + f * 16 + rl);
            al[f] = fragb(T1, kbl, wm + f * 16 + rl);
            bh[f] = fragb(T2, kbl, wn + f * 16 + rl);
            bl[f] = fragb(T3, kbl, wn + f * 16 + rl);
        }
#pragma unroll
        for (int i = 0; i < 4; ++i)
#pragma unroll
            for (int j = 0; j < 4; ++j) {
                acce[i][j] = MFMA16(al[i], bh[j], acce[i][j]);
                acce[i][j] = MFMA16(ah[i], bl[j], acce[i][j]);
                acce[i][j] = MFMA16(ah[i], bh[j], acce[i][j]);
            }
        __syncthreads();
    }

    // phase B: scores, single bf16 (reuses T0/T1)
    f32x4 accs[4][4] = {};
    for (int k0 = 0; k0 < DH; k0 += 32) {
        stage_b<4>(Q + zo + (size_t)m0 * DH + k0, DH, T0, lane, wid);
        stage_b<4>(Kb + zo + (size_t)n0 * DH + k0, DH, T1, lane, wid);
        __syncthreads();
        bf16x8 a[4], b[4];
#pragma unroll
        for (int f = 0; f < 4; ++f) {
            a[f] = fragb(T0, kbl, wm + f * 16 + rl);
            b[f] = fragb(T1, kbl, wn + f * 16 + rl);
        }
#pragma unroll
        for (int i = 0; i < 4; ++i)
#pragma unroll
            for (int j = 0; j < 4; ++j)
                accs[i][j] = MFMA16(a[i], b[j], accs[i][j]);
        __syncthreads();
    }

    // epilogue: EP + algebraic gate + masked S + per-(row, col-half) partials
    const size_t part = ((size_t)(z * 16 + blockIdx.x * 2 + (wn >> 6)) << 10);
#pragma unroll
    for (int i = 0; i < 4; ++i)
#pragma unroll
        for (int r = 0; r < 4; ++r) {
            const int m = m0 + wm + i * 16 + rw + r;
            float sv[4];
#pragma unroll
            for (int j = 0; j < 4; ++j) {
                const int n = n0 + wn + j * 16 + rl;
                const size_t idx = ((size_t)z << 20) + ((size_t)m << 10) + n;
                const float pp = 1.f / (1.f + __expf(-acce[i][j][r]));
                EP[idx] = pp;
                // reference gate zz>0 <=> (p+eps)(u+eps) > (1-p+eps)(1-u+eps)
                //                     <=> (p+u-1)(1+2eps) > 0 <=> p+u > 1
                const bool valid = (pp + U[idx] > 1.f) && (n < len);
                const float s_val = valid ? accs[i][j][r] * (1.f / 32.f) : NEGF;
                S[idx] = s_val;
                sv[j] = s_val;
            }
            // row partial over this 64-key half (16 lanes share the row)
            float mx = fmaxf(fmaxf(sv[0], sv[1]), fmaxf(sv[2], sv[3]));
#pragma unroll
            for (int off = 1; off <= 8; off <<= 1) mx = fmaxf(mx, __shfl_xor(mx, off));
            float ls = __expf(sv[0] - mx) + __expf(sv[1] - mx) +
                       __expf(sv[2] - mx) + __expf(sv[3] - mx);
#pragma unroll
            for (int off = 1; off <= 8; off <<= 1) ls += __shfl_xor(ls, off);
            if (rl == 0) { Sm[part + m] = mx; Sl[part + m] = ls; }
        }
}

// ---------------------------------------------------------------------------
// Fused softmax + ctx. Phase 1 combines the 16 per-half partials per row,
// then a SINGLE normalize pass in place. Phase 2: ctx = relu(P @ V).
// ---------------------------------------------------------------------------
__global__ __launch_bounds__(512) void softmax_ctx(float* __restrict__ P,
                                                   const float* __restrict__ Sm,
                                                   const float* __restrict__ Sl,
                                                   const short* __restrict__ Vt,
                                                   float* __restrict__ C) {
    __shared__ alignas(16) float Ps[4096];
    __shared__ alignas(16) short Vs[4096];
    const int z = blockIdx.y;
    const int bb = z >> 3, h = z & 7;
    const int m0 = blockIdx.x << 7;
    const int tid = threadIdx.x, lane = tid & 63, wid = tid >> 6;

    {
        const int r = tid >> 2, qd = tid & 3;
        const int row = m0 + r;
        // combine 16 half-tile partials for this row
        float M = -3.0e38f;
#pragma unroll
        for (int t = 0; t < 16; ++t) M = fmaxf(M, Sm[((size_t)(z * 16 + t) << 10) + row]);
        float L = 0.f;
#pragma unroll
        for (int t = 0; t < 16; ++t)
            L += Sl[((size_t)(z * 16 + t) << 10) + row] *
                 __expf(Sm[((size_t)(z * 16 + t) << 10) + row] - M);
        const float inv = (M > -5e29f) ? 1.f / L : 0.f;
        // single normalize pass
        float* rowp = P + ((size_t)z << 20) + ((size_t)row << 10) + qd * 8;
#pragma unroll 8
        for (int c = 0; c < 32; ++c) {
            float4 v0 = *reinterpret_cast<const float4*>(rowp + c * 32);
            float4 v1 = *reinterpret_cast<const float4*>(rowp + c * 32 + 4);
            v0.x = __expf(v0.x - M) * inv; v0.y = __expf(v0.y - M) * inv;
            v0.z = __expf(v0.z - M) * inv; v0.w = __expf(v0.w - M) * inv;
            v1.x = __expf(v1.x - M) * inv; v1.y = __expf(v1.y - M) * inv;
            v1.z = __expf(v1.z - M) * inv; v1.w = __expf(v1.w - M) * inv;
            *reinterpret_cast<float4*>(rowp + c * 32) = v0;
            *reinterpret_cast<float4*>(rowp + c * 32 + 4) = v1;
        }
    }
    __syncthreads();

    // phase 2: ctx GEMM
    const int wm = (wid >> 2) << 6, wn = (wid & 3) << 5;
    const int kbl = lane >> 4, rl = lane & 15, rw = (lane >> 4) << 2;
    f32x4 acc[4][2] = {};
    for (int k0 = 0; k0 < Tn; k0 += 32) {
        stage_f<8>(P + ((size_t)z << 20) + ((size_t)m0 << 10) + k0, Tn, Ps, lane, wid);
        stage_b<8>(Vt + ((size_t)z << 17) + k0, Tn, Vs, lane, wid);
        __syncthreads();
        bf16x8 a[4], b[2];
#pragma unroll
        for (int f = 0; f < 4; ++f) a[f] = fragf(Ps, kbl, wm + f * 16 + rl);
#pragma unroll
        for (int f = 0; f < 2; ++f) b[f] = fragb(Vs, kbl, wn + f * 16 + rl);
#pragma unroll
        for (int i = 0; i < 4; ++i)
#pragma unroll
            for (int j = 0; j < 2; ++j)
                acc[i][j] = MFMA16(a[i], b[j], acc[i][j]);
        __syncthreads();
    }
#pragma unroll
    for (int i = 0; i < 4; ++i)
#pragma unroll
        for (int r = 0; r < 4; ++r) {
            const int m = m0 + wm + i * 16 + rw + r;
#pragma unroll
            for (int j = 0; j < 2; ++j) {
                const int n = wn + j * 16 + rl;
                C[(((size_t)(bb << 10 | m)) << 10) + h * DH + n] = fmaxf(acc[i][j][r], 0.f);
            }
        }
}

// ---------------------------------------------------------------------------
// h1 = LN(ctx + masked_inputs); emits fp32 + bf16 (hi only)
// ---------------------------------------------------------------------------
__global__ __launch_bounds__(256) void ln1_kernel(const float* __restrict__ ctx,
                                                  const float* __restrict__ inputs,
                                                  const int* __restrict__ lengths,
                                                  const float* __restrict__ g,
                                                  const float* __restrict__ bb,
                                                  float* __restrict__ h1f,
                                                  short* __restrict__ h1hi) {
    __shared__ float red1[4];
    __shared__ float red2[4];
    const int row = blockIdx.x;
    const int t = row & 1023, b = row >> 10;
    const bool live = t < lengths[b];
    const size_t base = (size_t)row * Dn;
    const int tid = threadIdx.x;
    float4 v = reinterpret_cast<const float4*>(ctx + base)[tid];
    if (live) {
        const float4 r = reinterpret_cast<const float4*>(inputs + base)[tid];
        v.x += r.x; v.y += r.y; v.z += r.z; v.w += r.w;
    }
    float s = v.x + v.y + v.z + v.w;
#pragma unroll
    for (int off = 32; off >= 1; off >>= 1) s += __shfl_xor(s, off);
    if ((tid & 63) == 0) red1[tid >> 6] = s;
    __syncthreads();
    const float mu = (red1[0] + red1[1] + red1[2] + red1[3]) * (1.f / Dn);
    const float d0 = v.x - mu, d1 = v.y - mu, d2 = v.z - mu, d3 = v.w - mu;
    float sq = d0 * d0 + d1 * d1 + d2 * d2 + d3 * d3;
#pragma unroll
    for (int off = 32; off >= 1; off >>= 1) sq += __shfl_xor(sq, off);
    if ((tid & 63) == 0) red2[tid >> 6] = sq;
    __syncthreads();
    const float var = (red2[0] + red2[1] + red2[2] + red2[3]) * (1.f / Dn);
    const float rstd = rsqrtf(var + LN_EPSF);
    const float4 gv = reinterpret_cast<const float4*>(g)[tid];
    const float4 bv = reinterpret_cast<const float4*>(bb)[tid];
    float4 ov;
    ov.x = d0 * rstd * gv.x + bv.x;
    ov.y = d1 * rstd * gv.y + bv.y;
    ov.z = d2 * rstd * gv.z + bv.z;
    ov.w = d3 * rstd * gv.w + bv.w;
    reinterpret_cast<float4*>(h1f + base)[tid] = ov;
    short4 hs;
    hs.x = f2bf(ov.x); hs.y = f2bf(ov.y); hs.z = f2bf(ov.z); hs.w = f2bf(ov.w);
    reinterpret_cast<short4*>(h1hi + base)[tid] = hs;
}

// ---------------------------------------------------------------------------
// h2 = relu(h1 @ Wfc^T + bfc) + h1 ; single bf16; BK=64; 256 threads; 32KB LDS
// ---------------------------------------------------------------------------
__global__ __launch_bounds__(256) void fc_mfma(const short* __restrict__ Xh,
                                               const short* __restrict__ Wh,
                                               const float* __restrict__ bias,
                                               const float* __restrict__ H1f,
                                               float* __restrict__ O) {
    __shared__ alignas(16) short T0[8192];
    __shared__ alignas(16) short T1[8192];
    const int m0 = blockIdx.y << 7, n0 = blockIdx.x << 7;
    const int tid = threadIdx.x, lane = tid & 63, wid = tid >> 6;
    const int wm = (wid >> 1) << 6, wn = (wid & 1) << 6;
    const int kbl = lane >> 4, rl = lane & 15, rw = (lane >> 4) << 2;
    f32x4 acc[4][4] = {};
    for (int k0 = 0; k0 < Dn; k0 += 64) {
        stage64<256>(Xh + (size_t)m0 * Dn + k0, Dn, T0, lane, wid);
        stage64<256>(Wh + (size_t)n0 * Dn + k0, Dn, T1, lane, wid);
        __syncthreads();
#pragma unroll
        for (int hh = 0; hh < 2; ++hh) {
            bf16x8 a[4], b[4];
#pragma unroll
            for (int f = 0; f < 4; ++f) {
                a[f] = fragb(T0, hh * 4 + kbl, wm + f * 16 + rl);
                b[f] = fragb(T1, hh * 4 + kbl, wn + f * 16 + rl);
            }
#pragma unroll
            for (int i = 0; i < 4; ++i)
#pragma unroll
                for (int j = 0; j < 4; ++j)
                    acc[i][j] = MFMA16(a[i], b[j], acc[i][j]);
        }
        __syncthreads();
    }
#pragma unroll
    for (int i = 0; i < 4; ++i)
#pragma unroll
        for (int r = 0; r < 4; ++r) {
            const int m = m0 + wm + i * 16 + rw + r;
#pragma unroll
            for (int j = 0; j < 4; ++j) {
                const int n = n0 + wn + j * 16 + rl;
                const size_t idx = ((size_t)m << 10) + n;
                O[idx] = fmaxf(acc[i][j][r] + bias[n], 0.f) + H1f[idx];
            }
        }
}

// ---------------------------------------------------------------------------
// out = LN(h2), zero padded rows
// ---------------------------------------------------------------------------
__global__ __launch_bounds__(256) void ln2_kernel(const float* __restrict__ a,
                                                  const float* __restrict__ g,
                                                  const float* __restrict__ bb,
                                                  const int* __restrict__ lengths,
                                                  float* __restrict__ o) {
    __shared__ float red1[4];
    __shared__ float red2[4];
    const int row = blockIdx.x;
    const size_t base = (size_t)row * Dn;
    const int tid = threadIdx.x;
    float4 v = reinterpret_cast<const float4*>(a + base)[tid];
    float s = v.x + v.y + v.z + v.w;
#pragma unroll
    for (int off = 32; off >= 1; off >>= 1) s += __shfl_xor(s, off);
    if ((tid & 63) == 0) red1[tid >> 6] = s;
    __syncthreads();
    const float mu = (red1[0] + red1[1] + red1[2] + red1[3]) * (1.f / Dn);
    const float d0 = v.x - mu, d1 = v.y - mu, d2 = v.z - mu, d3 = v.w - mu;
    float sq = d0 * d0 + d1 * d1 + d2 * d2 + d3 * d3;
#pragma unroll
    for (int off = 32; off >= 1; off >>= 1) sq += __shfl_xor(sq, off);
    if ((tid & 63) == 0) red2[tid >> 6] = sq;
    __syncthreads();
    const float var = (red2[0] + red2[1] + red2[2] + red2[3]) * (1.f / Dn);
    const float rstd = rsqrtf(var + LN_EPSF);
    const float4 gv = reinterpret_cast<const float4*>(g)[tid];
    const float4 bv = reinterpret_cast<const float4*>(bb)[tid];
    float4 ov;
    ov.x = d0 * rstd * gv.x + bv.x;
    ov.y = d1 * rstd * gv.y + bv.y;
    ov.z = d2 * rstd * gv.z + bv.z;
    ov.w = d3 * rstd * gv.w + bv.w;
    const int t = row & 1023, b = row >> 10;
    if (t >= lengths[b]) { ov.x = 0.f; ov.y = 0.f; ov.z = 0.f; ov.w = 0.f; }
    reinterpret_cast<float4*>(o + base)[tid] = ov;
}

// ---------------------------------------------------------------------------
extern "C" void kernel_launch(void* const* d_in, const int* in_sizes, int n_in,
                              void* d_out, int out_size, void* d_ws, size_t ws_size,
                              hipStream_t stream) {
    const float* inputs = (const float*)d_in[0];
    const int* lengths = (const int*)d_in[1];
    const float* noise = (const float*)d_in[2];
    const float* bfc = (const float*)d_in[9];
    const float* ln1_g = (const float*)d_in[10];
    const float* ln1_b = (const float*)d_in[11];
    const float* ln2_g = (const float*)d_in[12];
    const float* ln2_b = (const float*)d_in[13];

    float* out = (float*)d_out;                       // (B,T,D)   4M f32
    float* attn = out + (size_t)Bn * Tn * Dn;         // (B,H,T,T) 32M f32
    float* ep = attn + (size_t)Bn * Hn * Tn * Tn;     // (B,H,T,T) 32M f32

    // workspace layout, peak 94 MB
    constexpr size_t MB = 1u << 20;
    char* W = (char*)d_ws;
    short* xhi = (short*)(W + 0 * MB);        //  8MB (dead after proj)
    short* xlo = (short*)(W + 8 * MB);        //  8MB (dead after proj)
    short* whi = (short*)(W + 16 * MB);       // 12MB hi of all 6 weights
    short* wlo = (short*)(W + 28 * MB);       //  4MB lo of Weq,Wek
    short* qb = (short*)(W + 34 * MB);        //  8MB (dead after scores_edge)
    short* kb = (short*)(W + 42 * MB);        //  8MB (dead after scores_edge)
    short* vtb = (short*)(W + 50 * MB);       //  8MB (dead after softmax_ctx)
    short* eqh = (short*)(W + 58 * MB);       //  8MB, dead after scores_edge
    short* eql = (short*)(W + 66 * MB);       //  8MB, dead after scores_edge
    short* ekh = (short*)(W + 74 * MB);       //  8MB, dead after scores_edge
    short* ekl = (short*)(W + 82 * MB);       //  8MB, dead after scores_edge
    float* ctx = (float*)(W + 58 * MB);       // 16MB reuse eqh+eql
    float* h1f = (float*)(W + 74 * MB);       // 16MB reuse ekh+ekl
    short* h1hi = (short*)(W + 34 * MB);      //  8MB reuse qb
    float* h2 = (float*)(W + 0 * MB);         // 16MB reuse xhi+xlo
    float* Sm = (float*)(W + 90 * MB);        //  2MB softmax half-tile maxes
    float* Sl = (float*)(W + 92 * MB);        //  2MB softmax half-tile expsums

    // K0: weights -> bf16 hi/lo
    CvtP cp;
    for (int j = 0; j < 6; ++j) cp.src[j] = (const float*)d_in[3 + j];
    cp.hi = whi; cp.lo = wlo;
    cvt_w<<<dim3(3072), 256, 0, stream>>>(cp);

    // K1: masked x -> split bf16
    mask_x<<<dim3(4096), 256, 0, stream>>>((const float4*)inputs, lengths, xhi, xlo);

    // K2a: q,k,v projections (single bf16, BK=64)
    Proj3P p3;
    p3.w[0] = whi;                 p3.o[0] = qb;
    p3.w[1] = whi + 1 * 1048576;   p3.o[1] = kb;
    p3.w[2] = whi + 2 * 1048576;   p3.o[2] = vtb;
    proj3_mfma<<<dim3(8, 32, 3), 256, 0, stream>>>(xhi, p3);

    // K2b: eq,ek projections (3-term split, BK=64, 512 threads)
    Proj2P p2;
    p2.wh[0] = whi + 3 * 1048576;  p2.wl[0] = wlo;
    p2.wh[1] = whi + 4 * 1048576;  p2.wl[1] = wlo + 1048576;
    p2.oh[0] = eqh; p2.ol[0] = eql;
    p2.oh[1] = ekh; p2.ol[1] = ekl;
    proj2_mfma<<<dim3(8, 32, 2), 512, 0, stream>>>(xhi, xlo, p2);

    // K3: edge(3-term)+scores, end-epilogue with algebraic gate + partials
    scores_edge<<<dim3(8, 8, 32), 256, 0, stream>>>(qb, kb, eqh, eql, ekh, ekl,
                                                    noise, lengths, attn, ep, Sm, Sl);

    // K4: softmax (combine 16 partials + single normalize pass) + ctx GEMM
    softmax_ctx<<<dim3(8, 32), 512, 0, stream>>>(attn, Sm, Sl, vtb, ctx);

    // K5: h1 = LN(ctx + masked inputs) -> fp32 + bf16
    ln1_kernel<<<dim3(Bn * Tn), 256, 0, stream>>>(ctx, inputs, lengths, ln1_g, ln1_b,
                                                  h1f, h1hi);

    // K6: h2 = relu(h1 @ Wfc^T + bfc) + h1 (single bf16, BK=64)
    fc_mfma<<<dim3(8, 32), 256, 0, stream>>>(h1hi, whi + 5 * 1048576, bfc, h1f, h2);

    // K7: out = LN(h2), zero padded rows
    ln2_kernel<<<dim3(Bn * Tn), 256, 0, stream>>>(h2, ln2_g, ln2_b, lengths, out);
}